// Round 4
// baseline (97.095 us; speedup 1.0000x reference)
//
#include <hip/hip_runtime.h>

#define BS 8192
#define D  128
#define TI 128              // i-rows per block (4 waves x 32)
#define TJ 128              // j-cols per block (staged once in LDS)
#define NJC (BS / TJ)       // 64 j-chunks (grid.y)
#define LDSR 136            // padded LDS row: 128 + 8 bf16 => 272 B (17*16B)

typedef __bf16 bf16x2 __attribute__((ext_vector_type(2)));
typedef __bf16 bf16x8 __attribute__((ext_vector_type(8)));
typedef float  f32x16 __attribute__((ext_vector_type(16)));

// ---------------------------------------------------------------------------
// prep: fp32 -> bf16 copies of anchor/positive, plus row reductions
//   a_sq[i] = ||anchor_i||^2, p_sq[j] = ||positive_j||^2,
//   pd2[i]  = ||anchor_i - positive_i||^2            (all exact fp32)
// ---------------------------------------------------------------------------
__global__ __launch_bounds__(256) void prep_kernel(
        const float* __restrict__ feats,
        __bf16* __restrict__ Abf, __bf16* __restrict__ Pbf,
        float* __restrict__ a_sq, float* __restrict__ p_sq,
        float* __restrict__ pd2)
{
    const int i = blockIdx.x * 4 + (threadIdx.x >> 6);   // 0..8191
    const int t = threadIdx.x & 63;                      // lane
    const float2 a = ((const float2*)(feats + (size_t)i * D))[t];
    const float2 p = ((const float2*)(feats + (size_t)(i + BS) * D))[t];

    bf16x2 ab; ab[0] = (__bf16)a.x; ab[1] = (__bf16)a.y;
    bf16x2 pb; pb[0] = (__bf16)p.x; pb[1] = (__bf16)p.y;
    ((bf16x2*)(Abf + (size_t)i * D))[t] = ab;
    ((bf16x2*)(Pbf + (size_t)i * D))[t] = pb;

    float sa = a.x * a.x + a.y * a.y;
    float sp = p.x * p.x + p.y * p.y;
    float d0 = a.x - p.x, d1 = a.y - p.y;
    float sd = d0 * d0 + d1 * d1;
    #pragma unroll
    for (int off = 32; off >= 1; off >>= 1) {
        sa += __shfl_xor(sa, off, 64);
        sp += __shfl_xor(sp, off, 64);
        sd += __shfl_xor(sd, off, 64);
    }
    if (t == 0) { a_sq[i] = sa; p_sq[i] = sp; pd2[i] = sd; }
}

// ---------------------------------------------------------------------------
// max kernel: block covers 128 i x 128 j. The full 128-row B panel is staged
// into padded LDS ONCE (single barrier), then 4 j-tiles x 8 MFMAs run with
// no further barriers. A fragments live in registers the whole kernel.
//
// Trick: acc is initialized to -p_sq[col]/2, so after the K-loop
//   acc = cross - p_sq/2, and min_j d2 = a_sq - 2 * max_j acc.
// Epilogue per tile is then a single v_max per accumulator register.
//
// mfma_f32_32x32x16_bf16 layouts (HW-verified, learn_hip m74/m101):
//   A: m = lane&31, k = (lane>>5)*8 + j
//   B: n = lane&31, k = (lane>>5)*8 + j
//   C/D: col = lane&31, row = (reg&3) + 8*(reg>>2) + 4*(lane>>5)
// ---------------------------------------------------------------------------
__global__ __launch_bounds__(256) void max_kernel(
        const __bf16* __restrict__ Abf, const __bf16* __restrict__ Pbf,
        const float* __restrict__ p_sq, float* __restrict__ partmax)
{
    __shared__ __bf16 smem[TJ * LDSR];          // 34816 B

    const int tid  = threadIdx.x;
    const int wave = tid >> 6;
    const int lane = tid & 63;
    const int l31  = lane & 31;
    const int half = lane >> 5;                 // 0 or 1

    const int i0    = blockIdx.x * TI + wave * 32;   // wave's 32 anchor rows
    const int jbase = blockIdx.y * TJ;

    // A fragments: row (i0+l31), k = s*16 + half*8 .. +8, for s = 0..7 (K=128)
    bf16x8 afrag[8];
    const __bf16* aptr = Abf + (size_t)(i0 + l31) * D + half * 8;
    #pragma unroll
    for (int s = 0; s < 8; ++s)
        afrag[s] = *reinterpret_cast<const bf16x8*>(aptr + s * 16);

    // ---- stage the whole B panel: 2048 x 16B pieces, 8 per thread,
    // coalesced global reads; piece q -> LDS row q>>4, col piece q&15 ----
    {
        const bf16x8* gsrc = (const bf16x8*)(Pbf + (size_t)jbase * D);
        bf16x8 tmp[8];
        #pragma unroll
        for (int h = 0; h < 8; ++h)
            tmp[h] = gsrc[tid + h * 256];
        #pragma unroll
        for (int h = 0; h < 8; ++h) {
            const int q = tid + h * 256;
            *reinterpret_cast<bf16x8*>(smem + (q >> 4) * LDSR + (q & 15) * 8) = tmp[h];
        }
    }
    __syncthreads();

    float rmax[16];
    #pragma unroll
    for (int r = 0; r < 16; ++r) rmax[r] = -3.0e38f;

    #pragma unroll
    for (int tile = 0; tile < TJ / 32; ++tile) {
        const float psq = p_sq[jbase + tile * 32 + l31];   // this lane's col
        const __bf16* lf = smem + (tile * 32 + l31) * LDSR + half * 8;

        f32x16 acc;
        const float cinit = -0.5f * psq;
        #pragma unroll
        for (int r = 0; r < 16; ++r) acc[r] = cinit;

        #pragma unroll
        for (int s = 0; s < 8; ++s) {
            bf16x8 bfrag = *reinterpret_cast<const bf16x8*>(lf + s * 16);
            acc = __builtin_amdgcn_mfma_f32_32x32x16_bf16(afrag[s], bfrag, acc,
                                                          0, 0, 0);
        }
        #pragma unroll
        for (int r = 0; r < 16; ++r)
            rmax[r] = fmaxf(rmax[r], acc[r]);
    }

    // max across the 32 columns (lanes sharing the same half)
    #pragma unroll
    for (int r = 0; r < 16; ++r) {
        float v = rmax[r];
        #pragma unroll
        for (int off = 1; off <= 16; off <<= 1)
            v = fmaxf(v, __shfl_xor(v, off, 64));
        rmax[r] = v;
    }
    if (l31 == 0) {
        float* dst = partmax + (size_t)blockIdx.y * BS + i0;
        #pragma unroll
        for (int r = 0; r < 16; ++r) {
            int row = (r & 3) + 8 * (r >> 2) + 4 * half;
            dst[row] = rmax[r];
        }
    }
}

// ---------------------------------------------------------------------------
// fin stage 1: 32 blocks x 256 threads; thread handles exactly one i.
// min_j d2 = a_sq[i] - 2 * max_c partmax[c][i]
// ---------------------------------------------------------------------------
__global__ __launch_bounds__(256) void fin1_kernel(
        const float* __restrict__ partmax, const float* __restrict__ a_sq,
        const float* __restrict__ pd2, float* __restrict__ bsum)
{
    __shared__ float ssum[4];
    const int t = threadIdx.x;
    const int i = blockIdx.x * 256 + t;

    float m = -3.0e38f;
    #pragma unroll
    for (int c = 0; c < NJC; ++c)
        m = fmaxf(m, partmax[c * BS + i]);
    float negd = sqrtf(fmaxf(fmaf(-2.0f, m, a_sq[i]), 0.0f));
    float posd = sqrtf(pd2[i]);
    float sum = fmaxf(posd - negd + 1.0f, 0.0f);

    #pragma unroll
    for (int off = 32; off >= 1; off >>= 1) sum += __shfl_xor(sum, off, 64);
    if ((t & 63) == 0) ssum[t >> 6] = sum;
    __syncthreads();
    if (t == 0)
        bsum[blockIdx.x] = ssum[0] + ssum[1] + ssum[2] + ssum[3];
}

// fin stage 2: one wave sums the 32 block partials.
__global__ __launch_bounds__(64) void fin2_kernel(
        const float* __restrict__ bsum, float* __restrict__ out)
{
    const int t = threadIdx.x;
    float v = (t < 32) ? bsum[t] : 0.0f;
    #pragma unroll
    for (int off = 32; off >= 1; off >>= 1) v += __shfl_xor(v, off, 64);
    if (t == 0) out[0] = v / (float)BS;
}

// ---------------------------------------------------------------------------
extern "C" void kernel_launch(void* const* d_in, const int* in_sizes, int n_in,
                              void* d_out, int out_size, void* d_ws,
                              size_t ws_size, hipStream_t stream)
{
    const float* feats = (const float*)d_in[0];

    char* ws = (char*)d_ws;
    __bf16* Abf   = (__bf16*)ws;  ws += (size_t)BS * D * 2;   // 2 MB
    __bf16* Pbf   = (__bf16*)ws;  ws += (size_t)BS * D * 2;   // 2 MB
    float* a_sq   = (float*)ws;   ws += (size_t)BS * 4;
    float* p_sq   = (float*)ws;   ws += (size_t)BS * 4;
    float* pd2    = (float*)ws;   ws += (size_t)BS * 4;
    float* partmax = (float*)ws;  ws += (size_t)NJC * BS * 4; // 2 MB
    float* bsum   = (float*)ws;   ws += 32 * 4;

    prep_kernel<<<BS / 4, 256, 0, stream>>>(feats, Abf, Pbf, a_sq, p_sq, pd2);
    dim3 grid(BS / TI, NJC);
    max_kernel<<<grid, 256, 0, stream>>>(Abf, Pbf, p_sq, partmax);
    fin1_kernel<<<BS / 256, 256, 0, stream>>>(partmax, a_sq, pd2, bsum);
    fin2_kernel<<<1, 64, 0, stream>>>(bsum, (float*)d_out);
}

// Round 5
// 85.524 us; speedup vs baseline: 1.1353x; 1.1353x over previous
//
#include <hip/hip_runtime.h>

#define BS 8192
#define D  128
#define TI 256              // i-rows per block (4 waves x 64)
#define JCHUNK 512          // j's per block (grid.y chunk)
#define NJC (BS / JCHUNK)   // 16 j-chunks
#define TJH 64              // rows per staged half-panel
#define NHP (JCHUNK / TJH)  // 8 half-panels per block
#define LDSR 136            // padded LDS row: 128 + 8 bf16 => 272 B (17*16B)
#define BUFE (TJH * LDSR)   // elems per LDS buffer (17408 B)

typedef __bf16 bf16x2 __attribute__((ext_vector_type(2)));
typedef __bf16 bf16x8 __attribute__((ext_vector_type(8)));
typedef float  f32x16 __attribute__((ext_vector_type(16)));

// ---------------------------------------------------------------------------
// prep: fp32 -> bf16 copies of anchor/positive, plus row reductions
//   a_sq[i] = ||anchor_i||^2, p_sq[j] = ||positive_j||^2,
//   pd2[i]  = ||anchor_i - positive_i||^2            (all exact fp32)
// ---------------------------------------------------------------------------
__global__ __launch_bounds__(256) void prep_kernel(
        const float* __restrict__ feats,
        __bf16* __restrict__ Abf, __bf16* __restrict__ Pbf,
        float* __restrict__ a_sq, float* __restrict__ p_sq,
        float* __restrict__ pd2)
{
    const int i = blockIdx.x * 4 + (threadIdx.x >> 6);   // 0..8191
    const int t = threadIdx.x & 63;                      // lane
    const float2 a = ((const float2*)(feats + (size_t)i * D))[t];
    const float2 p = ((const float2*)(feats + (size_t)(i + BS) * D))[t];

    bf16x2 ab; ab[0] = (__bf16)a.x; ab[1] = (__bf16)a.y;
    bf16x2 pb; pb[0] = (__bf16)p.x; pb[1] = (__bf16)p.y;
    ((bf16x2*)(Abf + (size_t)i * D))[t] = ab;
    ((bf16x2*)(Pbf + (size_t)i * D))[t] = pb;

    float sa = a.x * a.x + a.y * a.y;
    float sp = p.x * p.x + p.y * p.y;
    float d0 = a.x - p.x, d1 = a.y - p.y;
    float sd = d0 * d0 + d1 * d1;
    #pragma unroll
    for (int off = 32; off >= 1; off >>= 1) {
        sa += __shfl_xor(sa, off, 64);
        sp += __shfl_xor(sp, off, 64);
        sd += __shfl_xor(sd, off, 64);
    }
    if (t == 0) { a_sq[i] = sa; p_sq[i] = sp; pd2[i] = sd; }
}

// ---------------------------------------------------------------------------
// max kernel: block = 256 i-rows x 512 j-chunk. Each wave owns 64 i-rows
// (two A-fragment sets in registers -> each B-fragment LDS read feeds TWO
// MFMAs, halving LDS read traffic). The j-chunk streams as 8 half-panels of
// 64 rows through double-buffered padded LDS; panel hp+1 is prefetched into
// VGPRs while hp computes; one barrier per half-panel (32 MFMAs/wave between
// barriers).
//
// acc initialized to -p_sq[col]/2, so after K-loop acc = cross - p_sq/2 and
// min_j d2 = a_sq - 2 * max_j acc  -> epilogue is a single v_max per reg.
//
// mfma_f32_32x32x16_bf16 layouts (HW-verified, learn_hip m74/m101):
//   A: m = lane&31, k = (lane>>5)*8 + j
//   B: n = lane&31, k = (lane>>5)*8 + j
//   C/D: col = lane&31, row = (reg&3) + 8*(reg>>2) + 4*(lane>>5)
// ---------------------------------------------------------------------------
__global__ __launch_bounds__(256, 2) void max_kernel(
        const __bf16* __restrict__ Abf, const __bf16* __restrict__ Pbf,
        const float* __restrict__ p_sq, float* __restrict__ partmax)
{
    __shared__ __bf16 smem[2 * BUFE];           // 34816 B

    const int tid  = threadIdx.x;
    const int wave = tid >> 6;
    const int lane = tid & 63;
    const int l31  = lane & 31;
    const int half = lane >> 5;                 // 0 or 1

    const int i0    = blockIdx.x * TI + wave * 64;    // wave's 64 anchor rows
    const int jbase = blockIdx.y * JCHUNK;

    // Two A-fragment sets: rows i0+l31 and i0+32+l31, k = s*16 + half*8 ..
    bf16x8 afA[8], afB[8];
    {
        const __bf16* aA = Abf + (size_t)(i0 + l31) * D + half * 8;
        #pragma unroll
        for (int s = 0; s < 8; ++s) {
            afA[s] = *(const bf16x8*)(aA + s * 16);
            afB[s] = *(const bf16x8*)(aA + 32 * D + s * 16);
        }
    }

    // cinit[pt] = -p_sq[jbase + pt*32 + l31]/2 for the 16 32-col groups
    float cinit[16];
    #pragma unroll
    for (int pt = 0; pt < 16; ++pt)
        cinit[pt] = -0.5f * p_sq[jbase + pt * 32 + l31];

    float rmaxA[16], rmaxB[16];
    #pragma unroll
    for (int r = 0; r < 16; ++r) { rmaxA[r] = -3.0e38f; rmaxB[r] = -3.0e38f; }

    // stage half-panel 0: 1024 x 16B pieces, 4/thread, coalesced reads;
    // piece q -> LDS row q>>4, col piece q&15 (padded stride, 0-conflict)
    bf16x8 tmp[4];
    {
        const bf16x8* g = (const bf16x8*)(Pbf + (size_t)jbase * D);
        #pragma unroll
        for (int h = 0; h < 4; ++h) tmp[h] = g[tid + h * 256];
        #pragma unroll
        for (int h = 0; h < 4; ++h) {
            const int q = tid + h * 256;
            *(bf16x8*)(smem + (q >> 4) * LDSR + (q & 15) * 8) = tmp[h];
        }
    }
    __syncthreads();

    #pragma unroll 2
    for (int hp = 0; hp < NHP; ++hp) {
        // prefetch next half-panel into VGPRs (drains during compute)
        if (hp + 1 < NHP) {
            const bf16x8* g =
                (const bf16x8*)(Pbf + (size_t)(jbase + (hp + 1) * TJH) * D);
            #pragma unroll
            for (int h = 0; h < 4; ++h) tmp[h] = g[tid + h * 256];
        }

        const __bf16* buf = smem + (hp & 1) * BUFE;
        #pragma unroll
        for (int t = 0; t < 2; ++t) {
            const __bf16* lf = buf + (t * 32 + l31) * LDSR + half * 8;
            const float ci = cinit[hp * 2 + t];
            f32x16 acc0, acc1;
            #pragma unroll
            for (int r = 0; r < 16; ++r) { acc0[r] = ci; acc1[r] = ci; }
            #pragma unroll
            for (int s = 0; s < 8; ++s) {
                bf16x8 b = *(const bf16x8*)(lf + s * 16);
                acc0 = __builtin_amdgcn_mfma_f32_32x32x16_bf16(afA[s], b, acc0,
                                                               0, 0, 0);
                acc1 = __builtin_amdgcn_mfma_f32_32x32x16_bf16(afB[s], b, acc1,
                                                               0, 0, 0);
            }
            #pragma unroll
            for (int r = 0; r < 16; ++r) {
                rmaxA[r] = fmaxf(rmaxA[r], acc0[r]);
                rmaxB[r] = fmaxf(rmaxB[r], acc1[r]);
            }
        }

        // write next half-panel into the other buffer; one barrier per panel.
        // (last reads of that buffer were in iteration hp-1, already fenced
        // by that iteration's barrier)
        if (hp + 1 < NHP) {
            __bf16* wbuf = smem + ((hp + 1) & 1) * BUFE;
            #pragma unroll
            for (int h = 0; h < 4; ++h) {
                const int q = tid + h * 256;
                *(bf16x8*)(wbuf + (q >> 4) * LDSR + (q & 15) * 8) = tmp[h];
            }
            __syncthreads();
        }
    }

    // max across the 32 columns (lanes sharing the same half)
    #pragma unroll
    for (int r = 0; r < 16; ++r) {
        float vA = rmaxA[r], vB = rmaxB[r];
        #pragma unroll
        for (int off = 1; off <= 16; off <<= 1) {
            vA = fmaxf(vA, __shfl_xor(vA, off, 64));
            vB = fmaxf(vB, __shfl_xor(vB, off, 64));
        }
        rmaxA[r] = vA; rmaxB[r] = vB;
    }
    if (l31 == 0) {
        float* dst = partmax + (size_t)blockIdx.y * BS + i0;
        #pragma unroll
        for (int r = 0; r < 16; ++r) {
            int row = (r & 3) + 8 * (r >> 2) + 4 * half;
            dst[row]      = rmaxA[r];
            dst[row + 32] = rmaxB[r];
        }
    }
}

// ---------------------------------------------------------------------------
// fin stage 1: 32 blocks x 256 threads; thread handles exactly one i.
// min_j d2 = a_sq[i] - 2 * max_c partmax[c][i]
// ---------------------------------------------------------------------------
__global__ __launch_bounds__(256) void fin1_kernel(
        const float* __restrict__ partmax, const float* __restrict__ a_sq,
        const float* __restrict__ pd2, float* __restrict__ bsum)
{
    __shared__ float ssum[4];
    const int t = threadIdx.x;
    const int i = blockIdx.x * 256 + t;

    float m = -3.0e38f;
    #pragma unroll
    for (int c = 0; c < NJC; ++c)
        m = fmaxf(m, partmax[c * BS + i]);
    float negd = sqrtf(fmaxf(fmaf(-2.0f, m, a_sq[i]), 0.0f));
    float posd = sqrtf(pd2[i]);
    float sum = fmaxf(posd - negd + 1.0f, 0.0f);

    #pragma unroll
    for (int off = 32; off >= 1; off >>= 1) sum += __shfl_xor(sum, off, 64);
    if ((t & 63) == 0) ssum[t >> 6] = sum;
    __syncthreads();
    if (t == 0)
        bsum[blockIdx.x] = ssum[0] + ssum[1] + ssum[2] + ssum[3];
}

// fin stage 2: one wave sums the 32 block partials.
__global__ __launch_bounds__(64) void fin2_kernel(
        const float* __restrict__ bsum, float* __restrict__ out)
{
    const int t = threadIdx.x;
    float v = (t < 32) ? bsum[t] : 0.0f;
    #pragma unroll
    for (int off = 32; off >= 1; off >>= 1) v += __shfl_xor(v, off, 64);
    if (t == 0) out[0] = v / (float)BS;
}

// ---------------------------------------------------------------------------
extern "C" void kernel_launch(void* const* d_in, const int* in_sizes, int n_in,
                              void* d_out, int out_size, void* d_ws,
                              size_t ws_size, hipStream_t stream)
{
    const float* feats = (const float*)d_in[0];

    char* ws = (char*)d_ws;
    __bf16* Abf   = (__bf16*)ws;  ws += (size_t)BS * D * 2;   // 2 MB
    __bf16* Pbf   = (__bf16*)ws;  ws += (size_t)BS * D * 2;   // 2 MB
    float* a_sq   = (float*)ws;   ws += (size_t)BS * 4;
    float* p_sq   = (float*)ws;   ws += (size_t)BS * 4;
    float* pd2    = (float*)ws;   ws += (size_t)BS * 4;
    float* partmax = (float*)ws;  ws += (size_t)NJC * BS * 4; // 512 KB
    float* bsum   = (float*)ws;   ws += 32 * 4;

    prep_kernel<<<BS / 4, 256, 0, stream>>>(feats, Abf, Pbf, a_sq, p_sq, pd2);
    dim3 grid(BS / TI, NJC);
    max_kernel<<<grid, 256, 0, stream>>>(Abf, Pbf, p_sq, partmax);
    fin1_kernel<<<BS / 256, 256, 0, stream>>>(partmax, a_sq, pd2, bsum);
    fin2_kernel<<<1, 64, 0, stream>>>(bsum, (float*)d_out);
}